// Round 1
// baseline (100.974 us; speedup 1.0000x reference)
//
#include <hip/hip_runtime.h>

// SingleConstFilteredNormalized: y[i,j] = (x[i,j]!=0) ? f / row_sum(i) : 0
// where row_sum(i) = f * count_nonzero(x[i,:]), with safe=1 when row_sum==0.
// B=16384 rows, N=4096 cols, fp32 in/out. Memory-bound: 256MiB read + 256MiB write.

#define NCOL 4096
#define NV4  (NCOL / 4)      // 1024 float4 per row
#define BLK  256             // threads per block
#define PER_THREAD 4         // float4 loads per thread: 256*4*4 = 4096 elems

__global__ __launch_bounds__(BLK, 4)
void filt_norm_kernel(const float* __restrict__ x,
                      const float* __restrict__ f,
                      float* __restrict__ y,
                      int nrows) {
    __shared__ int   wsum[BLK / 64];
    __shared__ float sval;

    const int tid = threadIdx.x;
    const float fv = f[0];

    for (int row = blockIdx.x; row < nrows; row += gridDim.x) {
        const float4* __restrict__ xr = (const float4*)x + (size_t)row * NV4;
        float4*       __restrict__ yr = (float4*)y       + (size_t)row * NV4;

        // Load the whole row into registers (coalesced float4, 16B/lane).
        float4 v[PER_THREAD];
        #pragma unroll
        for (int k = 0; k < PER_THREAD; ++k)
            v[k] = xr[tid + k * BLK];

        // Per-thread nonzero count.
        int c = 0;
        #pragma unroll
        for (int k = 0; k < PER_THREAD; ++k) {
            c += (v[k].x != 0.0f);
            c += (v[k].y != 0.0f);
            c += (v[k].z != 0.0f);
            c += (v[k].w != 0.0f);
        }

        // Wave-64 reduce, then block reduce via LDS.
        #pragma unroll
        for (int off = 32; off > 0; off >>= 1)
            c += __shfl_down(c, off);
        if ((tid & 63) == 0) wsum[tid >> 6] = c;
        __syncthreads();
        if (tid == 0) {
            int cnt = wsum[0] + wsum[1] + wsum[2] + wsum[3];
            float rs = fv * (float)cnt;          // == reference's row_sum (to fp rounding)
            sval = fv / ((rs != 0.0f) ? rs : 1.0f);
        }
        __syncthreads();
        const float val = sval;

        // Masked write from registers (coalesced float4).
        #pragma unroll
        for (int k = 0; k < PER_THREAD; ++k) {
            float4 o;
            o.x = (v[k].x != 0.0f) ? val : 0.0f;
            o.y = (v[k].y != 0.0f) ? val : 0.0f;
            o.z = (v[k].z != 0.0f) ? val : 0.0f;
            o.w = (v[k].w != 0.0f) ? val : 0.0f;
            yr[tid + k * BLK] = o;
        }
        // sval/wsum reuse across iterations is safe: the second __syncthreads
        // orders this iteration's sval read before next iteration's wsum write,
        // and next iteration's sync1 orders its sval write after all reads here.
    }
}

extern "C" void kernel_launch(void* const* d_in, const int* in_sizes, int n_in,
                              void* d_out, int out_size, void* d_ws, size_t ws_size,
                              hipStream_t stream) {
    // inputs: d_in[0]=t (unused scalar), d_in[1]=x [B,N] f32, d_in[2]=f [1] f32
    const float* x = (const float*)d_in[1];
    const float* f = (const float*)d_in[2];
    float*       y = (float*)d_out;
    const int nrows = in_sizes[1] / NCOL;

    const int grid = 2048;   // grid-stride: 8 rows/block at B=16384
    filt_norm_kernel<<<grid, BLK, 0, stream>>>(x, f, y, nrows);
}

// Round 2
// 91.326 us; speedup vs baseline: 1.1056x; 1.1056x over previous
//
#include <hip/hip_runtime.h>
#include <cstdint>

// SingleConstFilteredNormalized: y[i,j] = (x[i,j]!=0) ? f / (f*cnt_i) : 0,
// cnt_i = #nonzeros in row i; safe=1 when f*cnt==0. B=16384, N=4096, fp32.
// Memory-bound: 256MiB read + 256MiB write. One WAVE per row: no LDS, no
// __syncthreads; row compressed to a 64-bit per-lane mask so load registers
// retire immediately (low VGPR -> high occupancy, deep load overlap).

#define NCOL 4096
#define NV4  (NCOL / 4)       // 1024 float4 per row
#define BLK  256              // 4 waves per block
#define WPB  4                // waves (rows) per block

typedef float f4 __attribute__((ext_vector_type(4)));

__global__ __launch_bounds__(BLK)
void filt_norm_kernel(const float* __restrict__ x,
                      const float* __restrict__ f,
                      float* __restrict__ y,
                      int nrows) {
    const int lane = threadIdx.x & 63;
    const int wid  = threadIdx.x >> 6;
    const int row  = blockIdx.x * WPB + wid;
    if (row >= nrows) return;

    const float fv = f[0];
    const f4* __restrict__ xr = (const f4*)x + (size_t)row * NV4;
    f4*       __restrict__ yr = (f4*)y       + (size_t)row * NV4;

    // 16 coalesced float4 loads per lane; compress each to 4 mask bits.
    uint64_t mask = 0;
    #pragma unroll
    for (int k = 0; k < 16; ++k) {
        f4 v = __builtin_nontemporal_load(xr + lane + k * 64);
        uint64_t m = 0;
        m |= (v.x != 0.0f) ? 1ull : 0ull;
        m |= (v.y != 0.0f) ? 2ull : 0ull;
        m |= (v.z != 0.0f) ? 4ull : 0ull;
        m |= (v.w != 0.0f) ? 8ull : 0ull;
        mask |= m << (k * 4);
    }

    // Wave-64 butterfly reduce of the nonzero count.
    int c = __popcll(mask);
    #pragma unroll
    for (int off = 32; off > 0; off >>= 1)
        c += __shfl_xor(c, off);

    const float rs  = fv * (float)c;            // == reference row_sum (fp-exact enough)
    const float val = fv / ((rs != 0.0f) ? rs : 1.0f);

    // Masked streaming write from the bit mask.
    #pragma unroll
    for (int k = 0; k < 16; ++k) {
        f4 o;
        o.x = ((mask >> (k * 4 + 0)) & 1ull) ? val : 0.0f;
        o.y = ((mask >> (k * 4 + 1)) & 1ull) ? val : 0.0f;
        o.z = ((mask >> (k * 4 + 2)) & 1ull) ? val : 0.0f;
        o.w = ((mask >> (k * 4 + 3)) & 1ull) ? val : 0.0f;
        __builtin_nontemporal_store(o, yr + lane + k * 64);
    }
}

extern "C" void kernel_launch(void* const* d_in, const int* in_sizes, int n_in,
                              void* d_out, int out_size, void* d_ws, size_t ws_size,
                              hipStream_t stream) {
    // inputs: d_in[0]=t (unused scalar), d_in[1]=x [B,N] f32, d_in[2]=f [1] f32
    const float* x = (const float*)d_in[1];
    const float* f = (const float*)d_in[2];
    float*       y = (float*)d_out;
    const int nrows = in_sizes[1] / NCOL;

    const int grid = (nrows + WPB - 1) / WPB;   // one wave per row
    filt_norm_kernel<<<grid, BLK, 0, stream>>>(x, f, y, nrows);
}